// Round 7
// baseline (878.524 us; speedup 1.0000x reference)
//
#include <hip/hip_runtime.h>
#include <hip/hip_bf16.h>
#include <stdint.h>
#include <stddef.h>

typedef __bf16 bf16;
typedef bf16  bf16x4 __attribute__((ext_vector_type(4)));
typedef bf16  bf16x8 __attribute__((ext_vector_type(8)));
typedef float f32x4  __attribute__((ext_vector_type(4)));

// ---------------------------------------------------------------------------
// async global->LDS, 16B per lane. LDS dest is wave-uniform base + lane*16.
// ---------------------------------------------------------------------------
__device__ __forceinline__ void async_copy16(bf16* lds, const bf16* g) {
    __builtin_amdgcn_global_load_lds(
        (const __attribute__((address_space(1))) void*)g,
        (__attribute__((address_space(3))) void*)lds,
        16, 0, 0);
}

__device__ __forceinline__ void bar() { __builtin_amdgcn_s_barrier(); }
#define SFENCE() __builtin_amdgcn_sched_barrier(0)
#define WAIT_VM0() do { asm volatile("s_waitcnt vmcnt(0)"); SFENCE(); } while (0)

// ---------------------------------------------------------------------------
// cast fp32 -> bf16, 4 elems/thread (unchanged)
// ---------------------------------------------------------------------------
__global__ __launch_bounds__(256) void cast_f32_to_bf16(
        const float* __restrict__ in, bf16* __restrict__ out, int n4) {
    int i = blockIdx.x * blockDim.x + threadIdx.x;
    if (i >= n4) return;
    const float4 v = *(const float4*)(in + (size_t)i * 4);
    bf16x4 o;
    o[0] = (bf16)v.x; o[1] = (bf16)v.y; o[2] = (bf16)v.z; o[3] = (bf16)v.w;
    *(bf16x4*)(out + (size_t)i * 4) = o;
}

// ---------------------------------------------------------------------------
// W_eff[n][k] = (q[n][k] - 7.5) * scale[n][k/64] + sum_r A[k][r]*Bm[r][n]
// (unchanged)
// ---------------------------------------------------------------------------
__global__ __launch_bounds__(256) void dequant_lora(
        const int*   __restrict__ q,
        const float* __restrict__ scale,
        const float* __restrict__ A,
        const float* __restrict__ Bm,
        bf16* __restrict__ out,
        int N, int K) {
    const int tid = threadIdx.x;
    const int k0 = blockIdx.x * 64;
    const int n0 = blockIdx.y * 64;
    const int kk = k0 + (tid & 15) * 4;
    const int nb = n0 + (tid >> 4) * 4;

    f32x4 Ar[4][4];
    #pragma unroll
    for (int i = 0; i < 4; ++i)
        #pragma unroll
        for (int rq = 0; rq < 4; ++rq)
            Ar[i][rq] = *(const f32x4*)&A[(size_t)(kk + i) * 16 + rq * 4];
    f32x4 Br[16];
    #pragma unroll
    for (int r = 0; r < 16; ++r)
        Br[r] = *(const f32x4*)&Bm[(size_t)r * N + nb];

    const int scol = (unsigned)k0 >> 6;
    #pragma unroll
    for (int nn = 0; nn < 4; ++nn) {
        const int n = nb + nn;
        const int4 qv = *(const int4*)&q[(size_t)n * K + kk];
        const float s = scale[(size_t)n * (K >> 6) + scol];
        float l0 = 0.f, l1 = 0.f, l2 = 0.f, l3 = 0.f;
        #pragma unroll
        for (int r = 0; r < 16; ++r) {
            const float bv = Br[r][nn];
            l0 += Ar[0][r >> 2][r & 3] * bv;
            l1 += Ar[1][r >> 2][r & 3] * bv;
            l2 += Ar[2][r >> 2][r & 3] * bv;
            l3 += Ar[3][r >> 2][r & 3] * bv;
        }
        bf16x4 o;
        o[0] = (bf16)(((float)qv.x - 7.5f) * s + l0);
        o[1] = (bf16)(((float)qv.y - 7.5f) * s + l1);
        o[2] = (bf16)(((float)qv.z - 7.5f) * s + l2);
        o[3] = (bf16)(((float)qv.w - 7.5f) * s + l3);
        *(bf16x4*)&out[(size_t)n * K + kk] = o;
    }
}

// ---------------------------------------------------------------------------
// gemm_bt v10: occupancy experiment re-expressed conservatively.
//
// Round-4 diagnosis: v8 = 5630 cyc/K-tile = MFMA(2480)+LDS(~2500)+barriers,
// fully SERIAL: ~252 regs/wave -> 1 block/CU -> every barrier stalls the CU.
// v9 (512thr, 2 blk/CU) never got a verdict (2x container failure, possibly
// kernel-induced). v10 tests the SAME hypothesis with minimal-risk config:
//
//   block 256 thr (4 waves, 2Mx2N), tile 128x128, BK=32, per-wave out 64x64
//   (acc 64 VGPR, frags 32) -> <=128 regs/wave; __launch_bounds__(256,4)
//   -> 4 blocks/CU, 16 waves/CU. LDS 32KB/block (4 blk x 32KB = 128KB/CU).
//
// Cross-BLOCK overlap replaces intra-block phase choreography: ONE barrier
// per K-tile; other resident blocks fill every stall (barriers per-block).
// Per K-tile per wave: 4 DMA (A2,B2), 8 ds_read_b128, 16 MFMA.
//   stage(t+1)->nxt ; ds_read cur ; MFMA (compiler counted lgkm) ;
//   vmcnt(0) [drains DMAs issued ~1 tile earlier => cheap] ; barrier.
// Single-barrier dbuf protocol soundness: every wave drains ITS OWN DMAs
// before barrier-arrival => post-barrier nxt fully resident (all waves) and
// cur fully read (MFMAs consumed reads pre-barrier) => re-stageable.
//
// Swizzle (row = 64B = 4 x 16B granules): granule g of row r stored at
// g ^ ((r>>1)&3). Involution applied on GLOBAL source (LDS dest stays
// linear per global_load_lds rule) and on ds_read address. Read pattern:
// 2 lanes/bank = free (m136).
// ---------------------------------------------------------------------------
template <bool RELU, typename OUT_T>
__global__ __launch_bounds__(256, 4) void gemm_bt(
        const bf16* __restrict__ A, const bf16* __restrict__ B,
        const float* __restrict__ bias, OUT_T* __restrict__ C,
        int M, int N, int K) {
    __shared__ __attribute__((aligned(16))) bf16 As0[4096];   // 128x32
    __shared__ __attribute__((aligned(16))) bf16 As1[4096];
    __shared__ __attribute__((aligned(16))) bf16 Bs0[4096];   // 128x32
    __shared__ __attribute__((aligned(16))) bf16 Bs1[4096];

    const int tid  = threadIdx.x;
    const int wave = tid >> 6;
    const int lane = tid & 63;
    const int wm   = wave >> 1;     // 0..1 : 64-row slice
    const int wn   = wave & 1;      // 0..1 : 64-col slice
    const int bn   = blockIdx.x;
    const int bm   = blockIdx.y;

    // staging: thread covers 16B-granule tid (rows 0..63) and tid+256
    // (rows 64..127) of each [128][32] buffer. Source granule pre-swizzled:
    // g' = (tid&3) ^ ((srow>>1)&3); (srow>>1)&3 identical for srow, srow+64.
    const int srow = tid >> 2;                               // 0..63
    const int scol = ((tid & 3) ^ ((tid >> 3) & 3)) * 8;     // elems
    const bf16* gA = A + ((size_t)(bm * 128) + srow) * K + scol;
    const bf16* gB = B + ((size_t)(bn * 128) + srow) * K + scol;
    const size_t rowskip = (size_t)64 * K;                   // uniform

    auto stageAB = [&](bf16* a0, bf16* b0, int t) {
        const bf16* sa = gA + (size_t)t * 32;
        const bf16* sb = gB + (size_t)t * 32;
        async_copy16(a0 + wave * 512, sa);                   // A rows 0..63
        async_copy16(a0 + 2048 + wave * 512, sa + rowskip);  // A rows 64..127
        async_copy16(b0 + wave * 512, sb);                   // B rows 0..63
        async_copy16(b0 + 2048 + wave * 512, sb + rowskip);  // B rows 64..127
    };

    // ds_read: lane (kq,fr) reads 16B at row = base+fr, granule
    // kq ^ ((fr>>1)&3)  [(row>>1)&3 == (fr>>1)&3: base multiple of 16].
    const int fr = lane & 15;
    const int kq = lane >> 4;
    const int ga = (kq ^ ((fr >> 1) & 3)) * 8;
    const int oA = (wm * 64 + fr) * 32 + ga;   // + i*512 per 16-row block
    const int oB = (wn * 64 + fr) * 32 + ga;   // + j*512 per 16-col block

    f32x4 acc[4][4];
    #pragma unroll
    for (int i = 0; i < 4; ++i)
        #pragma unroll
        for (int j = 0; j < 4; ++j) {
            f32x4 z = {0.f, 0.f, 0.f, 0.f};
            acc[i][j] = z;
        }

    // prologue: stage tile 0, drain, publish.
    stageAB(As0, Bs0, 0);
    WAIT_VM0();
    bar();

    const int NT = K >> 5;                     // 64 (gemm1) / 256 (gemm2)
    for (int t0 = 0; t0 < NT; t0 += 2) {
        #pragma unroll
        for (int u = 0; u < 2; ++u) {
            const int t = t0 + u;
            const bf16* aC = u ? As1 : As0;    // compile-time dbuf select
            const bf16* bC = u ? Bs1 : Bs0;
            bf16* aN = u ? As0 : As1;
            bf16* bN = u ? Bs0 : Bs1;

            // stage next tile first: maximize DMA latency cover (~1 tile).
            if (t + 1 < NT) stageAB(aN, bN, t + 1);

            bf16x8 fa[4], fb[4];
            #pragma unroll
            for (int i = 0; i < 4; ++i)
                fa[i] = *(const bf16x8*)(aC + oA + i * 512);
            #pragma unroll
            for (int j = 0; j < 4; ++j)
                fb[j] = *(const bf16x8*)(bC + oB + j * 512);

            __builtin_amdgcn_s_setprio(1);
            #pragma unroll
            for (int i = 0; i < 4; ++i)
                #pragma unroll
                for (int j = 0; j < 4; ++j)
                    acc[i][j] = __builtin_amdgcn_mfma_f32_16x16x32_bf16(
                        fa[i], fb[j], acc[i][j], 0, 0, 0);
            __builtin_amdgcn_s_setprio(0);

            // Drain own DMAs (issued one tile earlier) then publish.
            WAIT_VM0();
            bar();
        }
    }

    // epilogue: C/D layout col = lane&15, row = (lane>>4)*4 + reg (verified)
    const int er = bm * 128 + wm * 64 + (lane >> 4) * 4;
    const int ec = bn * 128 + wn * 64 + fr;
    #pragma unroll
    for (int j = 0; j < 4; ++j) {
        const int col = ec + j * 16;
        const float bv = bias[col];
        #pragma unroll
        for (int i = 0; i < 4; ++i) {
            #pragma unroll
            for (int r = 0; r < 4; ++r) {
                const int row = er + i * 16 + r;
                float v = acc[i][j][r] + bv;
                if (RELU) v = v > 0.f ? v : 0.f;
                C[(size_t)row * N + col] = (OUT_T)v;
            }
        }
    }
}

// ---------------------------------------------------------------------------
extern "C" void kernel_launch(void* const* d_in, const int* in_sizes, int n_in,
                              void* d_out, int out_size, void* d_ws, size_t ws_size,
                              hipStream_t stream) {
    const float* x1           = (const float*)d_in[0];
    const int*   w_up_q       = (const int*)  d_in[1];
    const float* w_up_scale   = (const float*)d_in[2];
    const float* b_up         = (const float*)d_in[3];
    const float* w_up_lora_a  = (const float*)d_in[4];
    const float* w_up_lora_b  = (const float*)d_in[5];
    const int*   w_down_q     = (const int*)  d_in[6];
    const float* w_down_scale = (const float*)d_in[7];
    const float* b_down       = (const float*)d_in[8];
    const float* w_down_lora_a= (const float*)d_in[9];
    const float* w_down_lora_b= (const float*)d_in[10];
    float* out = (float*)d_out;

    const int M = 8192, D = 2048, H = 8192;

    char* ws = (char*)d_ws;
    bf16* x1b = (bf16*)ws;                                   // M*D   (32 MB)
    bf16* wup = (bf16*)(ws + (size_t)M * D * 2);             // H*D   (32 MB)
    bf16* x2  = (bf16*)(ws + (size_t)M * D * 2 + (size_t)H * D * 2); // M*H (128 MB)
    bf16* wdn = x1b;  // reuse region 0 after gemm1 consumed x1b

    {
        int n4 = (M * D) / 4;
        cast_f32_to_bf16<<<dim3((n4 + 255) / 256), dim3(256), 0, stream>>>(x1, x1b, n4);
    }
    dequant_lora<<<dim3(D / 64, H / 64), dim3(256), 0, stream>>>(
        w_up_q, w_up_scale, w_up_lora_a, w_up_lora_b, wup, H, D);
    gemm_bt<true, bf16><<<dim3(H / 128, M / 128), dim3(256), 0, stream>>>(
        x1b, wup, b_up, x2, M, H, D);
    dequant_lora<<<dim3(H / 64, D / 64), dim3(256), 0, stream>>>(
        w_down_q, w_down_scale, w_down_lora_a, w_down_lora_b, wdn, D, H);
    gemm_bt<false, float><<<dim3(D / 128, M / 128), dim3(256), 0, stream>>>(
        x2, wdn, b_down, out, M, D, H);
}

// Round 8
// 771.329 us; speedup vs baseline: 1.1390x; 1.1390x over previous
//
#include <hip/hip_runtime.h>
#include <hip/hip_bf16.h>
#include <stdint.h>
#include <stddef.h>

typedef __bf16 bf16;
typedef bf16  bf16x4 __attribute__((ext_vector_type(4)));
typedef bf16  bf16x8 __attribute__((ext_vector_type(8)));
typedef float f32x4  __attribute__((ext_vector_type(4)));

// ---------------------------------------------------------------------------
// async global->LDS, 16B per lane. LDS dest is wave-uniform base + lane*16.
// ---------------------------------------------------------------------------
__device__ __forceinline__ void async_copy16(bf16* lds, const bf16* g) {
    __builtin_amdgcn_global_load_lds(
        (const __attribute__((address_space(1))) void*)g,
        (__attribute__((address_space(3))) void*)lds,
        16, 0, 0);
}

__device__ __forceinline__ void bar() { __builtin_amdgcn_s_barrier(); }
#define SFENCE() __builtin_amdgcn_sched_barrier(0)
#define WAIT_VM6()   do { asm volatile("s_waitcnt vmcnt(6)");   SFENCE(); } while (0)
#define WAIT_VM0()   do { asm volatile("s_waitcnt vmcnt(0)");   SFENCE(); } while (0)
#define THROTTLE_LGKM8() asm volatile("s_waitcnt lgkmcnt(8)")

// ---------------------------------------------------------------------------
// cast fp32 -> bf16, 4 elems/thread (unchanged)
// ---------------------------------------------------------------------------
__global__ __launch_bounds__(256) void cast_f32_to_bf16(
        const float* __restrict__ in, bf16* __restrict__ out, int n4) {
    int i = blockIdx.x * blockDim.x + threadIdx.x;
    if (i >= n4) return;
    const float4 v = *(const float4*)(in + (size_t)i * 4);
    bf16x4 o;
    o[0] = (bf16)v.x; o[1] = (bf16)v.y; o[2] = (bf16)v.z; o[3] = (bf16)v.w;
    *(bf16x4*)(out + (size_t)i * 4) = o;
}

// ---------------------------------------------------------------------------
// W_eff[n][k] = (q[n][k] - 7.5) * scale[n][k/64] + sum_r A[k][r]*Bm[r][n]
// (unchanged)
// ---------------------------------------------------------------------------
__global__ __launch_bounds__(256) void dequant_lora(
        const int*   __restrict__ q,
        const float* __restrict__ scale,
        const float* __restrict__ A,
        const float* __restrict__ Bm,
        bf16* __restrict__ out,
        int N, int K) {
    const int tid = threadIdx.x;
    const int k0 = blockIdx.x * 64;
    const int n0 = blockIdx.y * 64;
    const int kk = k0 + (tid & 15) * 4;
    const int nb = n0 + (tid >> 4) * 4;

    f32x4 Ar[4][4];
    #pragma unroll
    for (int i = 0; i < 4; ++i)
        #pragma unroll
        for (int rq = 0; rq < 4; ++rq)
            Ar[i][rq] = *(const f32x4*)&A[(size_t)(kk + i) * 16 + rq * 4];
    f32x4 Br[16];
    #pragma unroll
    for (int r = 0; r < 16; ++r)
        Br[r] = *(const f32x4*)&Bm[(size_t)r * N + nb];

    const int scol = (unsigned)k0 >> 6;
    #pragma unroll
    for (int nn = 0; nn < 4; ++nn) {
        const int n = nb + nn;
        const int4 qv = *(const int4*)&q[(size_t)n * K + kk];
        const float s = scale[(size_t)n * (K >> 6) + scol];
        float l0 = 0.f, l1 = 0.f, l2 = 0.f, l3 = 0.f;
        #pragma unroll
        for (int r = 0; r < 16; ++r) {
            const float bv = Br[r][nn];
            l0 += Ar[0][r >> 2][r & 3] * bv;
            l1 += Ar[1][r >> 2][r & 3] * bv;
            l2 += Ar[2][r >> 2][r & 3] * bv;
            l3 += Ar[3][r >> 2][r & 3] * bv;
        }
        bf16x4 o;
        o[0] = (bf16)(((float)qv.x - 7.5f) * s + l0);
        o[1] = (bf16)(((float)qv.y - 7.5f) * s + l1);
        o[2] = (bf16)(((float)qv.z - 7.5f) * s + l2);
        o[3] = (bf16)(((float)qv.w - 7.5f) * s + l3);
        *(bf16x4*)&out[(size_t)n * K + kk] = o;
    }
}

// ---------------------------------------------------------------------------
// gemm_bt256 v11: v8 base (measured 300us/gemm) + m201's BALANCED READ SPLIT.
//
// v8 read 16 ds_read_b128 in p1 (8fa+8fb burst: ~1536 cyc/CU of serialized
// LDS while the MFMA pipe idles under barrier-lockstep) because its stage
// schedule (B staged p2) forced all fb reads into p1. m201's template reads
// 12/4/8/0 and hits 62% MfmaUtil on the same structure (v8: 40%).
//
// v11 reads: p1 fa03+fb01 (12, + lgkmcnt(8) throttle), p2 fb23 (4),
// p3 fa47 (8), p4 none. Stage schedule reshuffled so cur-parity staging
// never overlaps a phase still reading that region:
//   p1: stage A-hi(t+1)->nxt          (nxt parity: always safe)
//   p3: stage B-lo(t+2)->cur          (B(t) reads drained end-p2)
//   p4: stage B-hi(t+2)+A-lo(t+2)->cur (A(t) reads drained end-p3)
// vmcnt ledger at p4 (steady state): pending = {B-lo,B-hi,A-lo}(t+1)[6] +
// A-hi(t+1)[2] + B-lo(t+2)[2] + B-hi(t+2)[2] + A-lo(t+2)[2] = 14 loads;
// vmcnt(6) retires 8 = ALL of tile t+1; 6 stay in flight across barriers.
// Min stage->drain slack 3 phases (~2000 cyc, covers HBM latency).
// MFMA quadrants: p1 Q0(fa03xfb01) p2 Q1(fa03xfb23) p3 Q2(fa47xfb23)
// p4 Q3(fa47xfb01) — fb01 lifetime spans to p4 exactly as in v8 (no new
// registers; v8 measured 124 VGPR, no spill).
// ---------------------------------------------------------------------------
template <bool RELU, typename OUT_T>
__global__ __launch_bounds__(512, 2) void gemm_bt256(
        const bf16* __restrict__ A, const bf16* __restrict__ B,
        const float* __restrict__ bias, OUT_T* __restrict__ C,
        int M, int N, int K) {
    __shared__ __attribute__((aligned(16))) bf16 As0[2][8192];
    __shared__ __attribute__((aligned(16))) bf16 As1[2][8192];
    __shared__ __attribute__((aligned(16))) bf16 Bs0[2][8192];
    __shared__ __attribute__((aligned(16))) bf16 Bs1[2][8192];

    const int tid  = threadIdx.x;
    const int wave = tid >> 6;
    const int lane = tid & 63;
    const int wm   = wave >> 2;     // 0..1 : row half of the 256-tile
    const int wn   = wave & 3;      // 0..3 : 64-col slice
    const int bn   = blockIdx.x;
    const int bm   = blockIdx.y;

    // staging: thread covers 16B-granules tid (rows 0..63) and tid+512
    // (rows 64..127) of each [128][64] half-tile; source col granule
    // pre-swizzled with the same involution the reads apply.
    const int srow = tid >> 3;
    const int scol = ((tid & 7) ^ (srow & 7)) * 8;   // elems
    const bf16* gA = A + ((size_t)(bm * 256) + srow) * K + scol;
    const bf16* gB = B + ((size_t)(bn * 256) + srow) * K + scol;

    auto stage2 = [&](bf16* halfBase, const bf16* g) {
        bf16* l = halfBase + wave * 512;             // wave-uniform dest
        async_copy16(l, g);
        async_copy16(l + 4096, g + (size_t)64 * K);  // rows +64
    };

    const int fr  = lane & 15;
    const int kq  = lane >> 4;
    const int cg0 = ((kq    ) ^ (fr & 7)) * 8;
    const int cg1 = ((kq + 4) ^ (fr & 7)) * 8;
    const int ra  = fr * 64;
    const int rb  = (wn & 1) * 4096 + fr * 64;       // 64-col offset in B half

    f32x4 acc[8][4];
    #pragma unroll
    for (int i = 0; i < 8; ++i)
        #pragma unroll
        for (int j = 0; j < 4; ++j) {
            f32x4 z = {0.f, 0.f, 0.f, 0.f};
            acc[i][j] = z;
        }

    // prologue: 7 half-tiles; first 4 (oldest) = all of tile 0.
    stage2(&Bs0[0][0], gB);
    stage2(&Bs0[1][0], gB + (size_t)128 * K);
    stage2(&As0[0][0], gA);
    stage2(&As0[1][0], gA + (size_t)128 * K);
    stage2(&Bs1[0][0], gB + 64);
    stage2(&Bs1[1][0], gB + (size_t)128 * K + 64);
    stage2(&As1[0][0], gA + 64);
    WAIT_VM6();                      // 14 issued, retire oldest 8 = tile 0
    bar();

    const int NT = K >> 6;
    bf16x8 fa[4][2], fb[4][2];

    for (int t0 = 0; t0 < NT; t0 += 2) {
        #pragma unroll
        for (int u = 0; u < 2; ++u) {
            const int t = t0 + u;
            bf16 (*AsC)[8192] = u ? As1 : As0;   // cur dbuf (t&1 == u)
            bf16 (*AsN)[8192] = u ? As0 : As1;   // next dbuf
            bf16 (*BsC)[8192] = u ? Bs1 : Bs0;
            const bf16* aC = &AsC[wm][0];
            const bf16* bC = &BsC[wn >> 1][0];

            // ---- phase 1: read fa03 + fb01 (12), stage A-hi(t+1) | Q0 ---
            #pragma unroll
            for (int i = 0; i < 4; ++i) {
                fa[i][0] = *(const bf16x8*)(aC + i * 1024 + ra + cg0);
                fa[i][1] = *(const bf16x8*)(aC + i * 1024 + ra + cg1);
            }
            #pragma unroll
            for (int j = 0; j < 2; ++j) {
                fb[j][0] = *(const bf16x8*)(bC + rb + j * 1024 + cg0);
                fb[j][1] = *(const bf16x8*)(bC + rb + j * 1024 + cg1);
            }
            if (t + 1 < NT)
                stage2(&AsN[1][0], gA + (size_t)128 * K + (size_t)(t + 1) * 64);
            THROTTLE_LGKM8();        // m201: cap ds queue when 12 reads
            bar();
            __builtin_amdgcn_s_setprio(1);
            #pragma unroll
            for (int ks = 0; ks < 2; ++ks)
                #pragma unroll
                for (int i = 0; i < 4; ++i)
                    #pragma unroll
                    for (int j = 0; j < 2; ++j)
                        acc[i][j] = __builtin_amdgcn_mfma_f32_16x16x32_bf16(
                            fa[i][ks], fb[j][ks], acc[i][j], 0, 0, 0);
            __builtin_amdgcn_s_setprio(0);
            bar();

            // ---- phase 2: read fb23 (4) | Q1 ----------------------------
            #pragma unroll
            for (int j = 2; j < 4; ++j) {
                fb[j][0] = *(const bf16x8*)(bC + rb + j * 1024 + cg0);
                fb[j][1] = *(const bf16x8*)(bC + rb + j * 1024 + cg1);
            }
            bar();
            __builtin_amdgcn_s_setprio(1);
            #pragma unroll
            for (int ks = 0; ks < 2; ++ks)
                #pragma unroll
                for (int i = 0; i < 4; ++i)
                    #pragma unroll
                    for (int j = 2; j < 4; ++j)
                        acc[i][j] = __builtin_amdgcn_mfma_f32_16x16x32_bf16(
                            fa[i][ks], fb[j][ks], acc[i][j], 0, 0, 0);
            __builtin_amdgcn_s_setprio(0);
            bar();

            // ---- phase 3: read fa47 (8), stage B-lo(t+2) | Q2 -----------
            #pragma unroll
            for (int i = 0; i < 4; ++i) {
                fa[i][0] = *(const bf16x8*)(aC + (i + 4) * 1024 + ra + cg0);
                fa[i][1] = *(const bf16x8*)(aC + (i + 4) * 1024 + ra + cg1);
            }
            if (t + 2 < NT)
                stage2(&BsC[0][0], gB + (size_t)(t + 2) * 64);  // B(t) read done end-p2
            bar();
            __builtin_amdgcn_s_setprio(1);
            #pragma unroll
            for (int ks = 0; ks < 2; ++ks)
                #pragma unroll
                for (int i = 0; i < 4; ++i)
                    #pragma unroll
                    for (int j = 2; j < 4; ++j)
                        acc[i + 4][j] = __builtin_amdgcn_mfma_f32_16x16x32_bf16(
                            fa[i][ks], fb[j][ks], acc[i + 4][j], 0, 0, 0);
            __builtin_amdgcn_s_setprio(0);
            bar();

            // ---- phase 4: stage B-hi(t+2)+A-lo(t+2), vmcnt(6) | Q3 ------
            if (t + 2 < NT) {
                stage2(&BsC[1][0], gB + (size_t)128 * K + (size_t)(t + 2) * 64);
                stage2(&AsC[0][0], gA + (size_t)(t + 2) * 64); // A(t) read done end-p3
                WAIT_VM6();          // retires ALL of tile t+1 (8 of 14)
            } else {
                WAIT_VM0();          // tail drain
            }
            bar();
            __builtin_amdgcn_s_setprio(1);
            #pragma unroll
            for (int ks = 0; ks < 2; ++ks)
                #pragma unroll
                for (int i = 0; i < 4; ++i)
                    #pragma unroll
                    for (int j = 0; j < 2; ++j)
                        acc[i + 4][j] = __builtin_amdgcn_mfma_f32_16x16x32_bf16(
                            fa[i][ks], fb[j][ks], acc[i + 4][j], 0, 0, 0);
            __builtin_amdgcn_s_setprio(0);
            bar();
        }
    }

    // epilogue: C/D layout col = lane&15, row = (lane>>4)*4 + reg (verified)
    const int er = bm * 256 + wm * 128 + (lane >> 4) * 4;
    const int ec = bn * 256 + wn * 64 + fr;
    #pragma unroll
    for (int j = 0; j < 4; ++j) {
        const int col = ec + j * 16;
        const float bv = bias[col];
        #pragma unroll
        for (int i = 0; i < 8; ++i) {
            #pragma unroll
            for (int r = 0; r < 4; ++r) {
                const int row = er + i * 16 + r;
                float v = acc[i][j][r] + bv;
                if (RELU) v = v > 0.f ? v : 0.f;
                C[(size_t)row * N + col] = (OUT_T)v;
            }
        }
    }
}

// ---------------------------------------------------------------------------
extern "C" void kernel_launch(void* const* d_in, const int* in_sizes, int n_in,
                              void* d_out, int out_size, void* d_ws, size_t ws_size,
                              hipStream_t stream) {
    const float* x1           = (const float*)d_in[0];
    const int*   w_up_q       = (const int*)  d_in[1];
    const float* w_up_scale   = (const float*)d_in[2];
    const float* b_up         = (const float*)d_in[3];
    const float* w_up_lora_a  = (const float*)d_in[4];
    const float* w_up_lora_b  = (const float*)d_in[5];
    const int*   w_down_q     = (const int*)  d_in[6];
    const float* w_down_scale = (const float*)d_in[7];
    const float* b_down       = (const float*)d_in[8];
    const float* w_down_lora_a= (const float*)d_in[9];
    const float* w_down_lora_b= (const float*)d_in[10];
    float* out = (float*)d_out;

    const int M = 8192, D = 2048, H = 8192;

    char* ws = (char*)d_ws;
    bf16* x1b = (bf16*)ws;                                   // M*D   (32 MB)
    bf16* wup = (bf16*)(ws + (size_t)M * D * 2);             // H*D   (32 MB)
    bf16* x2  = (bf16*)(ws + (size_t)M * D * 2 + (size_t)H * D * 2); // M*H (128 MB)
    bf16* wdn = x1b;  // reuse region 0 after gemm1 consumed x1b

    {
        int n4 = (M * D) / 4;
        cast_f32_to_bf16<<<dim3((n4 + 255) / 256), dim3(256), 0, stream>>>(x1, x1b, n4);
    }
    dequant_lora<<<dim3(D / 64, H / 64), dim3(256), 0, stream>>>(
        w_up_q, w_up_scale, w_up_lora_a, w_up_lora_b, wup, H, D);
    gemm_bt256<true, bf16><<<dim3(H / 256, M / 256), dim3(512), 0, stream>>>(
        x1b, wup, b_up, x2, M, H, D);
    dequant_lora<<<dim3(H / 64, D / 64), dim3(256), 0, stream>>>(
        w_down_q, w_down_scale, w_down_lora_a, w_down_lora_b, wdn, D, H);
    gemm_bt256<false, float><<<dim3(D / 256, M / 256), dim3(512), 0, stream>>>(
        x2, wdn, b_down, out, M, D, H);
}